// Round 15
// baseline (101.816 us; speedup 1.0000x reference)
//
#include <hip/hip_runtime.h>

// ---------------------------------------------------------------------------
// MultiHeadSelfAttention: B=4, L=2048, H=8, DK=DV=64, fp32 in/out.
// Reference quirks: logits *= sqrt(DK)=8 (multiply, not divide);
// ctx flattened dv-major (i = dv*H + h) before the final projection.
//
// v13 = v12 (r14, 99.0us PASS) + attn-only micro-opts:
//  - T5 s_setprio(1) around QK and PV MFMA clusters (guide m191: attn +4-7%)
//  - lsum via v_dot2_f32_f16 on f16 P pairs (2 ops vs 3 f32 adds; consistent
//    with PV numerator)
// SESSION RULES: barriers guarding global_load_lds must be explicit
// "s_waitcnt vmcnt(N); s_barrier" asm (__syncthreads does NOT drain
// global_load_lds -> v5/v9 failures). Ones-lsum-MFMA stays banned.
// ---------------------------------------------------------------------------

typedef _Float16 half2v __attribute__((ext_vector_type(2)));
typedef _Float16 half4v __attribute__((ext_vector_type(4)));
typedef _Float16 half8v __attribute__((ext_vector_type(8)));
typedef float    float4v __attribute__((ext_vector_type(4)));

#define BB   4
#define LL   2048
#define HH   8
#define DKV  64
#define NROW (BB * LL)            /* 8192 */
#define QSCALE 11.541560327111707f /* 8 * log2(e): folded into wq so the attn loop uses exp2 */

#define KVBLK 64
#define NEP   16                  /* epochs; each stages 2 tiles (one per kv-half) */

#define GLOAD_LDS(gp, sp) \
    __builtin_amdgcn_global_load_lds((const __attribute__((address_space(1))) void*)(gp), \
                                     (__attribute__((address_space(3))) void*)(sp), 16, 0, 0)

// ------- prep (merged): x->f16 ; Wt[1536][64]+bias ; wo2t[64][512] ----------
__global__ __launch_bounds__(256) void k_prep(const float* __restrict__ x,
                                              const float* __restrict__ wq, const float* __restrict__ bq,
                                              const float* __restrict__ wk, const float* __restrict__ bk,
                                              const float* __restrict__ wv, const float* __restrict__ bv,
                                              const float* __restrict__ wo,
                                              _Float16* __restrict__ xh,
                                              _Float16* __restrict__ wt, float* __restrict__ biasc,
                                              _Float16* __restrict__ wo2t) {
    int bidx = blockIdx.x;
    if (bidx < 512) {
        int i = bidx * 256 + threadIdx.x;             // NROW*64/4 = 131072
        float4v v = ((const float4v*)x)[i];
        half4v h;
        h[0] = (_Float16)v[0]; h[1] = (_Float16)v[1];
        h[2] = (_Float16)v[2]; h[3] = (_Float16)v[3];
        ((half4v*)xh)[i] = h;
    } else if (bidx < 896) {
        int idx = (bidx - 512) * 256 + threadIdx.x;   // 1536*64 = 98304
        int j = idx >> 6, i = idx & 63;
        const float* w; const float* bsrc; int jj; float sc = 1.0f;
        if (j < 512)       { w = wq; bsrc = bq; jj = j;        sc = QSCALE; }
        else if (j < 1024) { w = wk; bsrc = bk; jj = j - 512;  }
        else               { w = wv; bsrc = bv; jj = j - 1024; }
        wt[idx] = (_Float16)(w[i * 512 + jj] * sc);
        if (i == 0) biasc[j] = bsrc[jj] * sc;
    } else {
        int idx = (bidx - 896) * 256 + threadIdx.x;   // 64*512 = 32768
        int j = idx >> 9, k = idx & 511;
        int dv = k & 63, h = k >> 6;
        wo2t[idx] = (_Float16)wo[(dv * HH + h) * 64 + j];
    }
}

// ---------------- QKV projection GEMM: [8192,64] @ [64,1536] ----------------
// V is written directly TRANSPOSED into vt[bh][dv][l].
__global__ __launch_bounds__(256) void k_proj(const _Float16* __restrict__ xh,
                                              const _Float16* __restrict__ wt,
                                              const float* __restrict__ biasc,
                                              _Float16* __restrict__ qh,
                                              _Float16* __restrict__ kh,
                                              _Float16* __restrict__ vtw) {
    int wid = threadIdx.x >> 6, lane = threadIdx.x & 63;
    int g = lane >> 4, c = lane & 15;
    int m0 = blockIdx.x * 64 + wid * 16;
    int n0 = blockIdx.y * 64;

    half8v a0 = *(const half8v*)(xh + (m0 + c) * 64 + g * 8);
    half8v a1 = *(const half8v*)(xh + (m0 + c) * 64 + 32 + g * 8);

    float4v acc[4] = {};
#pragma unroll
    for (int t = 0; t < 4; ++t) {
        const _Float16* wp = wt + (n0 + t * 16 + c) * 64 + g * 8;
        half8v b0 = *(const half8v*)(wp);
        half8v b1 = *(const half8v*)(wp + 32);
        acc[t] = __builtin_amdgcn_mfma_f32_16x16x32_f16(a0, b0, acc[t], 0, 0, 0);
        acc[t] = __builtin_amdgcn_mfma_f32_16x16x32_f16(a1, b1, acc[t], 0, 0, 0);
    }
#pragma unroll
    for (int t = 0; t < 4; ++t) {
        int j = n0 + t * 16 + c;
        float bias = biasc[j];
        int mat = j >> 9, jj = j & 511, h = jj >> 6;
        if (mat == 2) {
            int b = m0 >> 11, l0 = m0 & 2047;
            half4v hv;
#pragma unroll
            for (int r = 0; r < 4; ++r) hv[r] = (_Float16)(acc[t][r] + bias);
            *(half4v*)(vtw + ((size_t)(b * 8 + h) * 64 + t * 16 + c) * 2048 + l0 + g * 4) = hv;
        } else {
            int cc = (t * 16 + c);
            _Float16* dst = (mat == 0) ? qh : kh;
#pragma unroll
            for (int r = 0; r < 4; ++r) {
                int m = m0 + g * 4 + r;
                int b = m >> 11, l = m & 2047;
                dst[((size_t)(b * HH + h) * LL + l) * 64 + cc] = (_Float16)(acc[t][r] + bias);
            }
        }
    }
}

// ---------------- flash attention v13: kv-split-2, 32 q-rows/wave ------------
// (= r13/r14 proven kernel + T5 setprio + fdot2 lsum)
__global__ __launch_bounds__(512, 4) void k_attn(const _Float16* __restrict__ qh,
                                                 const _Float16* __restrict__ kh,
                                                 const _Float16* __restrict__ vt,
                                                 _Float16* __restrict__ ctx) {
    // epoch buffer: [K0 8K][V0 8K][K1 8K][V1 8K] x2 double-buffer = 64KB
    __shared__ char lds[2 * 32768];

    int tid = threadIdx.x;
    int wid = tid >> 6, lane = tid & 63;
    int g = lane >> 4, c = lane & 15;
    int qw = wid & 3, half = wid >> 2;

    // 512 blocks: xcd = bid%8 -> 4 heads per XCD (K+V = 2MB, L2-resident)
    int bid = blockIdx.x;
    int xcd = bid & 7;
    int rest = bid >> 3;                  // 0..63
    int bh = xcd * 4 + (rest >> 4);       // 0..31
    int qc = rest & 15;                   // 16 chunks of 128 q-rows
    int q0 = qc * 128 + qw * 32;

    const _Float16* qp = qh + ((size_t)bh * LL + q0) * 64;
    const char* kg = (const char*)(kh + (size_t)bh * LL * 64);   // [L][64]: 8KB per KVBLK
    const char* vg = (const char*)(vt + (size_t)bh * 64 * LL);   // [dv=64][L]

    half8v qa0 = *(const half8v*)(qp + c * 64 + g * 8);
    half8v qa1 = *(const half8v*)(qp + c * 64 + 32 + g * 8);
    half8v qb0 = *(const half8v*)(qp + (16 + c) * 64 + g * 8);
    half8v qb1 = *(const half8v*)(qp + (16 + c) * 64 + 32 + g * 8);

    // ---- staging geometry (verbatim r9): 8 waves x 1KB per tile
    int pK   = wid * 1024 + lane * 16;            // byte offset in 8KB tile
    int rowS = pK >> 7;                           // tile row (128B rows)
    int srcK = (pK & ~127) | ((pK & 127) ^ ((rowS & 7) << 4));   // pre-swizzled source
    size_t srcV = (size_t)rowS * (LL * 2) + (size_t)((pK & 127) ^ ((rowS & 7) << 4));
    int pDst = wid * 1024;                        // HW adds lane*16

    // epoch e stages tile e (half0) and tile 16+e (half1)
#define STAGE(buf, e) do {                                                    \
        char* base = lds + (buf) * 32768;                                     \
        GLOAD_LDS(kg + (size_t)(e) * 8192 + srcK,        base + pDst);        \
        GLOAD_LDS(vg + srcV + (size_t)(e) * 128,         base + 8192 + pDst); \
        GLOAD_LDS(kg + (size_t)(16 + (e)) * 8192 + srcK, base + 16384 + pDst);\
        GLOAD_LDS(vg + srcV + (size_t)(16 + (e)) * 128,  base + 24576 + pDst);\
    } while (0)

    float4v oa[4] = {}, ob[4] = {};
    float ma = -1e30f, lsumA = 0.0f;
    float mb = -1e30f, lsumB = 0.0f;
    int swzk_c = (c & 7) << 4;
    half2v ones2;
    ones2[0] = ones2[1] = (_Float16)1.0f;

    STAGE(0, 0);

    for (int e = 0; e < NEP; ++e) {
        int cur = e & 1;
        if (e + 1 < NEP) {
            STAGE(cur ^ 1, e + 1);
            asm volatile("s_waitcnt vmcnt(4)" ::: "memory");
        } else {
            asm volatile("s_waitcnt vmcnt(0)" ::: "memory");
        }
        asm volatile("s_barrier" ::: "memory");

        const char* lk = lds + cur * 32768 + half * 16384;
        const char* lv = lk + 8192;

#pragma unroll
        for (int s = 0; s < 4; ++s) {
            int krow = s * 16 + c;
            int swzk = (krow & 7) << 4;
            half8v kf0 = *(const half8v*)(lk + krow * 128 + ((g * 16) ^ swzk));
            half8v kf1 = *(const half8v*)(lk + krow * 128 + ((g * 16 + 64) ^ swzk));

            __builtin_amdgcn_s_setprio(1);           // T5: favor MFMA cluster
            float4v sva = {};
            sva = __builtin_amdgcn_mfma_f32_16x16x32_f16(kf0, qa0, sva, 0, 0, 0);
            sva = __builtin_amdgcn_mfma_f32_16x16x32_f16(kf1, qa1, sva, 0, 0, 0);
            float4v svb = {};
            svb = __builtin_amdgcn_mfma_f32_16x16x32_f16(kf0, qb0, svb, 0, 0, 0);
            svb = __builtin_amdgcn_mfma_f32_16x16x32_f16(kf1, qb1, svb, 0, 0, 0);
            __builtin_amdgcn_s_setprio(0);

            // ---- softmax set A (skip-shfl steady state, r12-proven) ----
            float pmaxa = fmaxf(fmaxf(sva[0], sva[1]), fmaxf(sva[2], sva[3]));
            if (__any(pmaxa > ma + 3.0f)) {          // deferred rescale (T13)
                pmaxa = fmaxf(pmaxa, __shfl_xor(pmaxa, 16));
                pmaxa = fmaxf(pmaxa, __shfl_xor(pmaxa, 32));
                float mn = fmaxf(ma, pmaxa);
                float sc = __builtin_amdgcn_exp2f(ma - mn);
                lsumA *= sc;
#pragma unroll
                for (int t = 0; t < 4; ++t) oa[t] *= sc;
                ma = mn;
            }
            half4v pha;
            pha[0] = (_Float16)__builtin_amdgcn_exp2f(sva[0] - ma);
            pha[1] = (_Float16)__builtin_amdgcn_exp2f(sva[1] - ma);
            pha[2] = (_Float16)__builtin_amdgcn_exp2f(sva[2] - ma);
            pha[3] = (_Float16)__builtin_amdgcn_exp2f(sva[3] - ma);
            half2v pa01; pa01[0] = pha[0]; pa01[1] = pha[1];
            half2v pa23; pa23[0] = pha[2]; pa23[1] = pha[3];
            lsumA = __builtin_amdgcn_fdot2(pa01, ones2, lsumA, false);
            lsumA = __builtin_amdgcn_fdot2(pa23, ones2, lsumA, false);

            // ---- softmax set B ----
            float pmaxb = fmaxf(fmaxf(svb[0], svb[1]), fmaxf(svb[2], svb[3]));
            if (__any(pmaxb > mb + 3.0f)) {
                pmaxb = fmaxf(pmaxb, __shfl_xor(pmaxb, 16));
                pmaxb = fmaxf(pmaxb, __shfl_xor(pmaxb, 32));
                float mn = fmaxf(mb, pmaxb);
                float sc = __builtin_amdgcn_exp2f(mb - mn);
                lsumB *= sc;
#pragma unroll
                for (int t = 0; t < 4; ++t) ob[t] *= sc;
                mb = mn;
            }
            half4v phb;
            phb[0] = (_Float16)__builtin_amdgcn_exp2f(svb[0] - mb);
            phb[1] = (_Float16)__builtin_amdgcn_exp2f(svb[1] - mb);
            phb[2] = (_Float16)__builtin_amdgcn_exp2f(svb[2] - mb);
            phb[3] = (_Float16)__builtin_amdgcn_exp2f(svb[3] - mb);
            half2v pb01; pb01[0] = phb[0]; pb01[1] = phb[1];
            half2v pb23; pb23[0] = phb[2]; pb23[1] = phb[3];
            lsumB = __builtin_amdgcn_fdot2(pb01, ones2, lsumB, false);
            lsumB = __builtin_amdgcn_fdot2(pb23, ones2, lsumB, false);

            int vcol = (s * 32 + g * 8) ^ swzk_c;
            __builtin_amdgcn_s_setprio(1);           // T5: favor PV MFMA cluster
#pragma unroll
            for (int t = 0; t < 4; ++t) {
                half4v vf = *(const half4v*)(lv + (t * 16 + c) * 128 + vcol);
                oa[t] = __builtin_amdgcn_mfma_f32_16x16x16f16(vf, pha, oa[t], 0, 0, 0);
                ob[t] = __builtin_amdgcn_mfma_f32_16x16x16f16(vf, phb, ob[t], 0, 0, 0);
            }
            __builtin_amdgcn_s_setprio(0);
        }

        asm volatile("s_barrier" ::: "memory");
    }
#undef STAGE

    // ---- flash-merge of the two kv-halves via LDS (no global_load_lds in
    // flight here -> __syncthreads safe) --------------------------------------
    __syncthreads();
    if (half == 1) {
        float* mr = (float*)(lds + qw * 9216 + lane * 144);
#pragma unroll
        for (int t = 0; t < 4; ++t) *(float4v*)(mr + 4 * t) = oa[t];
#pragma unroll
        for (int t = 0; t < 4; ++t) *(float4v*)(mr + 16 + 4 * t) = ob[t];
        float4v sc; sc[0] = ma; sc[1] = lsumA; sc[2] = mb; sc[3] = lsumB;
        *(float4v*)(mr + 32) = sc;
    }
    __syncthreads();
    if (half == 0) {
        const float* mr = (const float*)(lds + qw * 9216 + lane * 144);
        float4v sc = *(const float4v*)(mr + 32);
        float ma2 = sc[0], la2 = sc[1], mb2 = sc[2], lb2 = sc[3];

        float mMA = fmaxf(ma, ma2);
        float s1a = __builtin_amdgcn_exp2f(ma - mMA);
        float s2a = __builtin_amdgcn_exp2f(ma2 - mMA);
        float mMB = fmaxf(mb, mb2);
        float s1b = __builtin_amdgcn_exp2f(mb - mMB);
        float s2b = __builtin_amdgcn_exp2f(mb2 - mMB);
#pragma unroll
        for (int t = 0; t < 4; ++t) {
            float4v o2 = *(const float4v*)(mr + 4 * t);
            oa[t] = oa[t] * s1a + o2 * s2a;
        }
#pragma unroll
        for (int t = 0; t < 4; ++t) {
            float4v o2 = *(const float4v*)(mr + 16 + 4 * t);
            ob[t] = ob[t] * s1b + o2 * s2b;
        }
        lsumA = lsumA * s1a + la2 * s2a;
        lsumB = lsumB * s1b + lb2 * s2b;

        lsumA += __shfl_xor(lsumA, 16);
        lsumA += __shfl_xor(lsumA, 32);
        lsumB += __shfl_xor(lsumB, 16);
        lsumB += __shfl_xor(lsumB, 32);
        float inva = 1.0f / lsumA;
        float invb = 1.0f / lsumB;

        _Float16* cpa = ctx + ((size_t)bh * LL + q0 + c) * 64 + g * 4;
        _Float16* cpb = cpa + 16 * 64;
#pragma unroll
        for (int t = 0; t < 4; ++t) {
            half4v hva, hvb;
#pragma unroll
            for (int r = 0; r < 4; ++r) {
                hva[r] = (_Float16)(oa[t][r] * inva);
                hvb[r] = (_Float16)(ob[t][r] * invb);
            }
            *(half4v*)(cpa + t * 16) = hva;
            *(half4v*)(cpb + t * 16) = hvb;
        }
    }
}

// ---------------- output projection: [8192,512] @ [512,64] ----------------
// r9-proven config: 512 blocks x 64 threads (2 blocks/CU spread).
__global__ __launch_bounds__(64) void k_oproj(const _Float16* __restrict__ ctx,
                                              const _Float16* __restrict__ wo2t,
                                              const float* __restrict__ bo,
                                              float* __restrict__ out) {
    int lane = threadIdx.x & 63;
    int g = lane >> 4, c = lane & 15;
    int m0 = blockIdx.x * 16;
    int b = m0 >> 11, l = m0 & 2047;
    const _Float16* cbase = ctx + ((size_t)b * HH * LL + l) * 64;

    float4v acc[4] = {};
#pragma unroll
    for (int kc = 0; kc < 16; ++kc) {
        int hh = kc >> 1;
        const _Float16* ap = cbase + (size_t)hh * LL * 64 + c * 64 + (kc & 1) * 32 + g * 8;
        half8v a = *(const half8v*)(ap);
#pragma unroll
        for (int t = 0; t < 4; ++t) {
            half8v bf = *(const half8v*)(wo2t + (t * 16 + c) * 512 + kc * 32 + g * 8);
            acc[t] = __builtin_amdgcn_mfma_f32_16x16x32_f16(a, bf, acc[t], 0, 0, 0);
        }
    }
#pragma unroll
    for (int t = 0; t < 4; ++t) {
        float bias = bo[t * 16 + c];
#pragma unroll
        for (int r = 0; r < 4; ++r) {
            int mm = m0 + g * 4 + r;
            out[mm * 64 + t * 16 + c] = acc[t][r] + bias;
        }
    }
}

// ---------------------------------------------------------------------------
extern "C" void kernel_launch(void* const* d_in, const int* in_sizes, int n_in,
                              void* d_out, int out_size, void* d_ws, size_t ws_size,
                              hipStream_t stream) {
    const float* x  = (const float*)d_in[0];
    const float* wq = (const float*)d_in[1];
    const float* bq = (const float*)d_in[2];
    const float* wk = (const float*)d_in[3];
    const float* bk = (const float*)d_in[4];
    const float* wv = (const float*)d_in[5];
    const float* bv = (const float*)d_in[6];
    const float* wo = (const float*)d_in[7];
    const float* bo = (const float*)d_in[8];
    float* out = (float*)d_out;

    char* ws = (char*)d_ws;
    _Float16* xh    = (_Float16*)(ws);                       // 1 MB
    _Float16* wt    = (_Float16*)(ws + 1048576);             // 192 KB
    float*    biasc = (float*)   (ws + 1245184);             // 6 KB
    _Float16* wo2t  = (_Float16*)(ws + 1251328);             // 64 KB
    _Float16* qh    = (_Float16*)(ws + 1316864);             // 8 MB
    _Float16* kh    = (_Float16*)(ws + 1316864 + 1ull * 8388608);
    _Float16* vt    = (_Float16*)(ws + 1316864 + 2ull * 8388608);
    _Float16* ctx   = (_Float16*)(ws + 1316864 + 3ull * 8388608);

    hipLaunchKernelGGL(k_prep,  dim3(1024),     dim3(256), 0, stream,
                       x, wq, bq, wk, bk, wv, bv, wo, xh, wt, biasc, wo2t);
    hipLaunchKernelGGL(k_proj,  dim3(128, 24),  dim3(256), 0, stream, xh, wt, biasc, qh, kh, vt);
    hipLaunchKernelGGL(k_attn,  dim3(512),      dim3(512), 0, stream, qh, kh, vt, ctx);
    hipLaunchKernelGGL(k_oproj, dim3(512),      dim3(64),  0, stream, ctx, wo2t, bo, out);
}

// Round 16
// 99.232 us; speedup vs baseline: 1.0260x; 1.0260x over previous
//
#include <hip/hip_runtime.h>

// ---------------------------------------------------------------------------
// MultiHeadSelfAttention: B=4, L=2048, H=8, DK=DV=64, fp32 in/out.
// Reference quirks: logits *= sqrt(DK)=8 (multiply, not divide);
// ctx flattened dv-major (i = dv*H + h) before the final projection.
//
// v14 = exact revert to r14 (session best: 99.0us total, attn 70.7us).
// r15's T5 setprio + fdot2 lsum bundle REGRESSED (-3us): setprio is
// structure-conditional (m190: negative on barrier-lockstep waves -- our
// regime); fdot2 serialized the lsum chain. Both reverted.
// SESSION RULES: barriers guarding global_load_lds must be explicit
// "s_waitcnt vmcnt(N); s_barrier" asm (__syncthreads does NOT drain
// global_load_lds -> v5/v9 failures). Ones-lsum-MFMA stays banned.
// ---------------------------------------------------------------------------

typedef _Float16 half4v __attribute__((ext_vector_type(4)));
typedef _Float16 half8v __attribute__((ext_vector_type(8)));
typedef float    float4v __attribute__((ext_vector_type(4)));

#define BB   4
#define LL   2048
#define HH   8
#define DKV  64
#define NROW (BB * LL)            /* 8192 */
#define QSCALE 11.541560327111707f /* 8 * log2(e): folded into wq so the attn loop uses exp2 */

#define KVBLK 64
#define NEP   16                  /* epochs; each stages 2 tiles (one per kv-half) */

#define GLOAD_LDS(gp, sp) \
    __builtin_amdgcn_global_load_lds((const __attribute__((address_space(1))) void*)(gp), \
                                     (__attribute__((address_space(3))) void*)(sp), 16, 0, 0)

// ------- prep (merged): x->f16 ; Wt[1536][64]+bias ; wo2t[64][512] ----------
__global__ __launch_bounds__(256) void k_prep(const float* __restrict__ x,
                                              const float* __restrict__ wq, const float* __restrict__ bq,
                                              const float* __restrict__ wk, const float* __restrict__ bk,
                                              const float* __restrict__ wv, const float* __restrict__ bv,
                                              const float* __restrict__ wo,
                                              _Float16* __restrict__ xh,
                                              _Float16* __restrict__ wt, float* __restrict__ biasc,
                                              _Float16* __restrict__ wo2t) {
    int bidx = blockIdx.x;
    if (bidx < 512) {
        int i = bidx * 256 + threadIdx.x;             // NROW*64/4 = 131072
        float4v v = ((const float4v*)x)[i];
        half4v h;
        h[0] = (_Float16)v[0]; h[1] = (_Float16)v[1];
        h[2] = (_Float16)v[2]; h[3] = (_Float16)v[3];
        ((half4v*)xh)[i] = h;
    } else if (bidx < 896) {
        int idx = (bidx - 512) * 256 + threadIdx.x;   // 1536*64 = 98304
        int j = idx >> 6, i = idx & 63;
        const float* w; const float* bsrc; int jj; float sc = 1.0f;
        if (j < 512)       { w = wq; bsrc = bq; jj = j;        sc = QSCALE; }
        else if (j < 1024) { w = wk; bsrc = bk; jj = j - 512;  }
        else               { w = wv; bsrc = bv; jj = j - 1024; }
        wt[idx] = (_Float16)(w[i * 512 + jj] * sc);
        if (i == 0) biasc[j] = bsrc[jj] * sc;
    } else {
        int idx = (bidx - 896) * 256 + threadIdx.x;   // 64*512 = 32768
        int j = idx >> 9, k = idx & 511;
        int dv = k & 63, h = k >> 6;
        wo2t[idx] = (_Float16)wo[(dv * HH + h) * 64 + j];
    }
}

// ---------------- QKV projection GEMM: [8192,64] @ [64,1536] ----------------
// V is written directly TRANSPOSED into vt[bh][dv][l].
__global__ __launch_bounds__(256) void k_proj(const _Float16* __restrict__ xh,
                                              const _Float16* __restrict__ wt,
                                              const float* __restrict__ biasc,
                                              _Float16* __restrict__ qh,
                                              _Float16* __restrict__ kh,
                                              _Float16* __restrict__ vtw) {
    int wid = threadIdx.x >> 6, lane = threadIdx.x & 63;
    int g = lane >> 4, c = lane & 15;
    int m0 = blockIdx.x * 64 + wid * 16;
    int n0 = blockIdx.y * 64;

    half8v a0 = *(const half8v*)(xh + (m0 + c) * 64 + g * 8);
    half8v a1 = *(const half8v*)(xh + (m0 + c) * 64 + 32 + g * 8);

    float4v acc[4] = {};
#pragma unroll
    for (int t = 0; t < 4; ++t) {
        const _Float16* wp = wt + (n0 + t * 16 + c) * 64 + g * 8;
        half8v b0 = *(const half8v*)(wp);
        half8v b1 = *(const half8v*)(wp + 32);
        acc[t] = __builtin_amdgcn_mfma_f32_16x16x32_f16(a0, b0, acc[t], 0, 0, 0);
        acc[t] = __builtin_amdgcn_mfma_f32_16x16x32_f16(a1, b1, acc[t], 0, 0, 0);
    }
#pragma unroll
    for (int t = 0; t < 4; ++t) {
        int j = n0 + t * 16 + c;
        float bias = biasc[j];
        int mat = j >> 9, jj = j & 511, h = jj >> 6;
        if (mat == 2) {
            int b = m0 >> 11, l0 = m0 & 2047;
            half4v hv;
#pragma unroll
            for (int r = 0; r < 4; ++r) hv[r] = (_Float16)(acc[t][r] + bias);
            *(half4v*)(vtw + ((size_t)(b * 8 + h) * 64 + t * 16 + c) * 2048 + l0 + g * 4) = hv;
        } else {
            int cc = (t * 16 + c);
            _Float16* dst = (mat == 0) ? qh : kh;
#pragma unroll
            for (int r = 0; r < 4; ++r) {
                int m = m0 + g * 4 + r;
                int b = m >> 11, l = m & 2047;
                dst[((size_t)(b * HH + h) * LL + l) * 64 + cc] = (_Float16)(acc[t][r] + bias);
            }
        }
    }
}

// ---------------- flash attention (= r13/r14 proven kernel) ------------------
__global__ __launch_bounds__(512, 4) void k_attn(const _Float16* __restrict__ qh,
                                                 const _Float16* __restrict__ kh,
                                                 const _Float16* __restrict__ vt,
                                                 _Float16* __restrict__ ctx) {
    // epoch buffer: [K0 8K][V0 8K][K1 8K][V1 8K] x2 double-buffer = 64KB
    __shared__ char lds[2 * 32768];

    int tid = threadIdx.x;
    int wid = tid >> 6, lane = tid & 63;
    int g = lane >> 4, c = lane & 15;
    int qw = wid & 3, half = wid >> 2;

    // 512 blocks: xcd = bid%8 -> 4 heads per XCD (K+V = 2MB, L2-resident)
    int bid = blockIdx.x;
    int xcd = bid & 7;
    int rest = bid >> 3;                  // 0..63
    int bh = xcd * 4 + (rest >> 4);       // 0..31
    int qc = rest & 15;                   // 16 chunks of 128 q-rows
    int q0 = qc * 128 + qw * 32;

    const _Float16* qp = qh + ((size_t)bh * LL + q0) * 64;
    const char* kg = (const char*)(kh + (size_t)bh * LL * 64);   // [L][64]: 8KB per KVBLK
    const char* vg = (const char*)(vt + (size_t)bh * 64 * LL);   // [dv=64][L]

    half8v qa0 = *(const half8v*)(qp + c * 64 + g * 8);
    half8v qa1 = *(const half8v*)(qp + c * 64 + 32 + g * 8);
    half8v qb0 = *(const half8v*)(qp + (16 + c) * 64 + g * 8);
    half8v qb1 = *(const half8v*)(qp + (16 + c) * 64 + 32 + g * 8);

    // ---- staging geometry (verbatim r9): 8 waves x 1KB per tile
    int pK   = wid * 1024 + lane * 16;            // byte offset in 8KB tile
    int rowS = pK >> 7;                           // tile row (128B rows)
    int srcK = (pK & ~127) | ((pK & 127) ^ ((rowS & 7) << 4));   // pre-swizzled source
    size_t srcV = (size_t)rowS * (LL * 2) + (size_t)((pK & 127) ^ ((rowS & 7) << 4));
    int pDst = wid * 1024;                        // HW adds lane*16

    // epoch e stages tile e (half0) and tile 16+e (half1)
#define STAGE(buf, e) do {                                                    \
        char* base = lds + (buf) * 32768;                                     \
        GLOAD_LDS(kg + (size_t)(e) * 8192 + srcK,        base + pDst);        \
        GLOAD_LDS(vg + srcV + (size_t)(e) * 128,         base + 8192 + pDst); \
        GLOAD_LDS(kg + (size_t)(16 + (e)) * 8192 + srcK, base + 16384 + pDst);\
        GLOAD_LDS(vg + srcV + (size_t)(16 + (e)) * 128,  base + 24576 + pDst);\
    } while (0)

    float4v oa[4] = {}, ob[4] = {};
    float ma = -1e30f, lsumA = 0.0f;
    float mb = -1e30f, lsumB = 0.0f;
    int swzk_c = (c & 7) << 4;

    STAGE(0, 0);

    for (int e = 0; e < NEP; ++e) {
        int cur = e & 1;
        if (e + 1 < NEP) {
            STAGE(cur ^ 1, e + 1);
            asm volatile("s_waitcnt vmcnt(4)" ::: "memory");
        } else {
            asm volatile("s_waitcnt vmcnt(0)" ::: "memory");
        }
        asm volatile("s_barrier" ::: "memory");

        const char* lk = lds + cur * 32768 + half * 16384;
        const char* lv = lk + 8192;

#pragma unroll
        for (int s = 0; s < 4; ++s) {
            int krow = s * 16 + c;
            int swzk = (krow & 7) << 4;
            half8v kf0 = *(const half8v*)(lk + krow * 128 + ((g * 16) ^ swzk));
            half8v kf1 = *(const half8v*)(lk + krow * 128 + ((g * 16 + 64) ^ swzk));

            float4v sva = {};
            sva = __builtin_amdgcn_mfma_f32_16x16x32_f16(kf0, qa0, sva, 0, 0, 0);
            sva = __builtin_amdgcn_mfma_f32_16x16x32_f16(kf1, qa1, sva, 0, 0, 0);
            float4v svb = {};
            svb = __builtin_amdgcn_mfma_f32_16x16x32_f16(kf0, qb0, svb, 0, 0, 0);
            svb = __builtin_amdgcn_mfma_f32_16x16x32_f16(kf1, qb1, svb, 0, 0, 0);

            // ---- softmax set A (skip-shfl steady state, r12-proven) ----
            float pmaxa = fmaxf(fmaxf(sva[0], sva[1]), fmaxf(sva[2], sva[3]));
            if (__any(pmaxa > ma + 3.0f)) {          // deferred rescale (T13)
                pmaxa = fmaxf(pmaxa, __shfl_xor(pmaxa, 16));
                pmaxa = fmaxf(pmaxa, __shfl_xor(pmaxa, 32));
                float mn = fmaxf(ma, pmaxa);
                float sc = __builtin_amdgcn_exp2f(ma - mn);
                lsumA *= sc;
#pragma unroll
                for (int t = 0; t < 4; ++t) oa[t] *= sc;
                ma = mn;
            }
            float pa0 = __builtin_amdgcn_exp2f(sva[0] - ma);
            float pa1 = __builtin_amdgcn_exp2f(sva[1] - ma);
            float pa2 = __builtin_amdgcn_exp2f(sva[2] - ma);
            float pa3 = __builtin_amdgcn_exp2f(sva[3] - ma);
            lsumA += (pa0 + pa1) + (pa2 + pa3);
            half4v pha;
            pha[0] = (_Float16)pa0; pha[1] = (_Float16)pa1;
            pha[2] = (_Float16)pa2; pha[3] = (_Float16)pa3;

            // ---- softmax set B ----
            float pmaxb = fmaxf(fmaxf(svb[0], svb[1]), fmaxf(svb[2], svb[3]));
            if (__any(pmaxb > mb + 3.0f)) {
                pmaxb = fmaxf(pmaxb, __shfl_xor(pmaxb, 16));
                pmaxb = fmaxf(pmaxb, __shfl_xor(pmaxb, 32));
                float mn = fmaxf(mb, pmaxb);
                float sc = __builtin_amdgcn_exp2f(mb - mn);
                lsumB *= sc;
#pragma unroll
                for (int t = 0; t < 4; ++t) ob[t] *= sc;
                mb = mn;
            }
            float pb0 = __builtin_amdgcn_exp2f(svb[0] - mb);
            float pb1 = __builtin_amdgcn_exp2f(svb[1] - mb);
            float pb2 = __builtin_amdgcn_exp2f(svb[2] - mb);
            float pb3 = __builtin_amdgcn_exp2f(svb[3] - mb);
            lsumB += (pb0 + pb1) + (pb2 + pb3);
            half4v phb;
            phb[0] = (_Float16)pb0; phb[1] = (_Float16)pb1;
            phb[2] = (_Float16)pb2; phb[3] = (_Float16)pb3;

            int vcol = (s * 32 + g * 8) ^ swzk_c;
#pragma unroll
            for (int t = 0; t < 4; ++t) {
                half4v vf = *(const half4v*)(lv + (t * 16 + c) * 128 + vcol);
                oa[t] = __builtin_amdgcn_mfma_f32_16x16x16f16(vf, pha, oa[t], 0, 0, 0);
                ob[t] = __builtin_amdgcn_mfma_f32_16x16x16f16(vf, phb, ob[t], 0, 0, 0);
            }
        }

        asm volatile("s_barrier" ::: "memory");
    }
#undef STAGE

    // ---- flash-merge of the two kv-halves via LDS (no global_load_lds in
    // flight here -> __syncthreads safe) --------------------------------------
    __syncthreads();
    if (half == 1) {
        float* mr = (float*)(lds + qw * 9216 + lane * 144);
#pragma unroll
        for (int t = 0; t < 4; ++t) *(float4v*)(mr + 4 * t) = oa[t];
#pragma unroll
        for (int t = 0; t < 4; ++t) *(float4v*)(mr + 16 + 4 * t) = ob[t];
        float4v sc; sc[0] = ma; sc[1] = lsumA; sc[2] = mb; sc[3] = lsumB;
        *(float4v*)(mr + 32) = sc;
    }
    __syncthreads();
    if (half == 0) {
        const float* mr = (const float*)(lds + qw * 9216 + lane * 144);
        float4v sc = *(const float4v*)(mr + 32);
        float ma2 = sc[0], la2 = sc[1], mb2 = sc[2], lb2 = sc[3];

        float mMA = fmaxf(ma, ma2);
        float s1a = __builtin_amdgcn_exp2f(ma - mMA);
        float s2a = __builtin_amdgcn_exp2f(ma2 - mMA);
        float mMB = fmaxf(mb, mb2);
        float s1b = __builtin_amdgcn_exp2f(mb - mMB);
        float s2b = __builtin_amdgcn_exp2f(mb2 - mMB);
#pragma unroll
        for (int t = 0; t < 4; ++t) {
            float4v o2 = *(const float4v*)(mr + 4 * t);
            oa[t] = oa[t] * s1a + o2 * s2a;
        }
#pragma unroll
        for (int t = 0; t < 4; ++t) {
            float4v o2 = *(const float4v*)(mr + 16 + 4 * t);
            ob[t] = ob[t] * s1b + o2 * s2b;
        }
        lsumA = lsumA * s1a + la2 * s2a;
        lsumB = lsumB * s1b + lb2 * s2b;

        lsumA += __shfl_xor(lsumA, 16);
        lsumA += __shfl_xor(lsumA, 32);
        lsumB += __shfl_xor(lsumB, 16);
        lsumB += __shfl_xor(lsumB, 32);
        float inva = 1.0f / lsumA;
        float invb = 1.0f / lsumB;

        _Float16* cpa = ctx + ((size_t)bh * LL + q0 + c) * 64 + g * 4;
        _Float16* cpb = cpa + 16 * 64;
#pragma unroll
        for (int t = 0; t < 4; ++t) {
            half4v hva, hvb;
#pragma unroll
            for (int r = 0; r < 4; ++r) {
                hva[r] = (_Float16)(oa[t][r] * inva);
                hvb[r] = (_Float16)(ob[t][r] * invb);
            }
            *(half4v*)(cpa + t * 16) = hva;
            *(half4v*)(cpb + t * 16) = hvb;
        }
    }
}

// ---------------- output projection: [8192,512] @ [512,64] ----------------
// r9-proven config: 512 blocks x 64 threads (2 blocks/CU spread).
__global__ __launch_bounds__(64) void k_oproj(const _Float16* __restrict__ ctx,
                                              const _Float16* __restrict__ wo2t,
                                              const float* __restrict__ bo,
                                              float* __restrict__ out) {
    int lane = threadIdx.x & 63;
    int g = lane >> 4, c = lane & 15;
    int m0 = blockIdx.x * 16;
    int b = m0 >> 11, l = m0 & 2047;
    const _Float16* cbase = ctx + ((size_t)b * HH * LL + l) * 64;

    float4v acc[4] = {};
#pragma unroll
    for (int kc = 0; kc < 16; ++kc) {
        int hh = kc >> 1;
        const _Float16* ap = cbase + (size_t)hh * LL * 64 + c * 64 + (kc & 1) * 32 + g * 8;
        half8v a = *(const half8v*)(ap);
#pragma unroll
        for (int t = 0; t < 4; ++t) {
            half8v bf = *(const half8v*)(wo2t + (t * 16 + c) * 512 + kc * 32 + g * 8);
            acc[t] = __builtin_amdgcn_mfma_f32_16x16x32_f16(a, bf, acc[t], 0, 0, 0);
        }
    }
#pragma unroll
    for (int t = 0; t < 4; ++t) {
        float bias = bo[t * 16 + c];
#pragma unroll
        for (int r = 0; r < 4; ++r) {
            int mm = m0 + g * 4 + r;
            out[mm * 64 + t * 16 + c] = acc[t][r] + bias;
        }
    }
}

// ---------------------------------------------------------------------------
extern "C" void kernel_launch(void* const* d_in, const int* in_sizes, int n_in,
                              void* d_out, int out_size, void* d_ws, size_t ws_size,
                              hipStream_t stream) {
    const float* x  = (const float*)d_in[0];
    const float* wq = (const float*)d_in[1];
    const float* bq = (const float*)d_in[2];
    const float* wk = (const float*)d_in[3];
    const float* bk = (const float*)d_in[4];
    const float* wv = (const float*)d_in[5];
    const float* bv = (const float*)d_in[6];
    const float* wo = (const float*)d_in[7];
    const float* bo = (const float*)d_in[8];
    float* out = (float*)d_out;

    char* ws = (char*)d_ws;
    _Float16* xh    = (_Float16*)(ws);                       // 1 MB
    _Float16* wt    = (_Float16*)(ws + 1048576);             // 192 KB
    float*    biasc = (float*)   (ws + 1245184);             // 6 KB
    _Float16* wo2t  = (_Float16*)(ws + 1251328);             // 64 KB
    _Float16* qh    = (_Float16*)(ws + 1316864);             // 8 MB
    _Float16* kh    = (_Float16*)(ws + 1316864 + 1ull * 8388608);
    _Float16* vt    = (_Float16*)(ws + 1316864 + 2ull * 8388608);
    _Float16* ctx   = (_Float16*)(ws + 1316864 + 3ull * 8388608);

    hipLaunchKernelGGL(k_prep,  dim3(1024),     dim3(256), 0, stream,
                       x, wq, bq, wk, bk, wv, bv, wo, xh, wt, biasc, wo2t);
    hipLaunchKernelGGL(k_proj,  dim3(128, 24),  dim3(256), 0, stream, xh, wt, biasc, qh, kh, vt);
    hipLaunchKernelGGL(k_attn,  dim3(512),      dim3(512), 0, stream, qh, kh, vt, ctx);
    hipLaunchKernelGGL(k_oproj, dim3(512),      dim3(64),  0, stream, ctx, wo2t, bo, out);
}